// Round 16
// baseline (168.214 us; speedup 1.0000x reference)
//
#include <hip/hip_runtime.h>

// ---- problem constants ----
#define IN_C  16
#define OUT_C 32
#define NB 2
#define TT 8
#define DD 8
#define HH 32
#define WW 32
#define TP 10
#define DP 10
#define HP 34
#define WPAD 34

// xt layout: [n][tp][dp][hp][icblk(2)][w(34)][ic8] bf16 ; row = 1088 B
#define XT_ROW_B  1088
#define XT_ELEMS  (NB*TP*DP*HP*2*WPAD*8)     // 3,699,200 bf16 = 7,398,400 B
// wt layout: [tap(84 padded)][icblk(2)][oc(32)][ic8] bf16 ; taps 81..83 zeroed
#define WT_TAPS_P 84
#define WT_ELEMS  (WT_TAPS_P*2*OUT_C*8)      // 43,008 bf16 = 86,016 B

#define A_SLAB_B 12288
#define B_CHUNK_B 28672

typedef __bf16 bf16x8 __attribute__((ext_vector_type(8)));
typedef float  f32x4  __attribute__((ext_vector_type(4)));
typedef float  f32x16 __attribute__((ext_vector_type(16)));

__device__ __forceinline__ unsigned short f2bf(float f) {
    unsigned int u = __builtin_bit_cast(unsigned int, f);
    u += 0x7fffu + ((u >> 16) & 1u);       // RNE
    return (unsigned short)(u >> 16);
}

__device__ __forceinline__ void gload16(const void* g, void* l) {
    __builtin_amdgcn_global_load_lds(
        (const __attribute__((address_space(1))) unsigned int*)g,
        (__attribute__((address_space(3))) unsigned int*)l, 16, 0, 0);
}

// ---------------- fused prep: xpose rows + halo zeroing + weight xform ----------------
__global__ __launch_bounds__(256) void prep_kernel(const float* __restrict__ x,
                                                   const float* __restrict__ wsrc,
                                                   unsigned short* __restrict__ xt,
                                                   unsigned short* __restrict__ wt) {
    int b = blockIdx.x;
    int tid = threadIdx.x;
    if (b < 4096) {
        __shared__ unsigned short ls[WW * IN_C];   // [w][c], 1 KiB
        int h = b & 31, d = (b >> 5) & 7, t = (b >> 8) & 7, n = b >> 11;
        int c = tid >> 5, w = tid & 31;
        float v0 = x[((((size_t)(n * IN_C + c)     * TT + t) * DD + d) * HH + h) * WW + w];
        float v1 = x[((((size_t)(n * IN_C + c + 8) * TT + t) * DD + d) * HH + h) * WW + w];
        ls[w * 16 + c]     = f2bf(v0);
        ls[w * 16 + c + 8] = f2bf(v1);
        __syncthreads();
        if (tid < 68) {
            int blk = tid / 34, wl = tid % 34;
            unsigned char* row = (unsigned char*)xt +
                (size_t)(((n * TP + t + 1) * DP + d + 1) * HP + h + 1) * XT_ROW_B;
            f32x4 val = {0.f, 0.f, 0.f, 0.f};
            if (wl != 0 && wl != 33)
                val = *(const f32x4*)((const unsigned char*)ls + (wl - 1) * 32 + blk * 16);
            *(f32x4*)(row + tid * 16) = val;
        }
    } else if (b < 6800) {
        int j = b - 4096;
        int n, tp, dp, hp;
        if (j < 1360)      { n = j / 680;  int r = j % 680;  tp = (r / 340) * 9; int r2 = r % 340; dp = r2 / 34;       hp = r2 % 34; }
        else if (j < 2448) { int j2 = j - 1360; n = j2 / 544; int r = j2 % 544; tp = 1 + r / 68;  int r3 = r % 68;  dp = (r3 / 34) * 9; hp = r3 % 34; }
        else               { int j3 = j - 2448; n = j3 / 128; int r = j3 % 128; tp = 1 + r / 16;  int r4 = r % 16;  dp = 1 + r4 / 2;   hp = (r4 & 1) * 33; }
        if (tid < 68) {
            unsigned char* row = (unsigned char*)xt +
                (size_t)(((n * TP + tp) * DP + dp) * HP + hp) * XT_ROW_B;
            f32x4 z = {0.f, 0.f, 0.f, 0.f};
            *(f32x4*)(row + tid * 16) = z;
        }
    } else {
        int idx = (b - 6800) * 256 + tid;
        int tap = idx >> 9;
        int r = idx & 511;
        int icblk = r >> 8, oc = (r >> 3) & 31, i8 = r & 7;
        int ic = icblk * 8 + i8;
        float v = (tap < 81) ? wsrc[(oc * IN_C + ic) * 81 + tap] : 0.0f;
        wt[idx] = f2bf(v);
    }
}

// ================= REAL conv: R10 verbatim (best known, 26.5us total) =================
__global__ __launch_bounds__(256, 2) void conv_main_kernel(const unsigned short* __restrict__ xt,
                                                           const unsigned short* __restrict__ wt,
                                                           const float* __restrict__ bias,
                                                           float* __restrict__ out) {
    __shared__ __align__(16) unsigned char As0[A_SLAB_B];
    __shared__ __align__(16) unsigned char As1[A_SLAB_B];
    __shared__ __align__(16) unsigned char Bs0[B_CHUNK_B];
    __shared__ __align__(16) unsigned char Bs1[B_CHUNK_B];

    int bid = blockIdx.x;
    int lb  = (bid & 7) * 64 + (bid >> 3);
    int hb = lb & 3, d = (lb >> 2) & 7, t = (lb >> 5) & 7, n = lb >> 8;
    int h0 = hb * 8;
    int tid  = threadIdx.x;
    int wv   = tid >> 6;
    int lane = tid & 63;
    int l31  = lane & 31;
    int kblk = lane >> 5;

    int ab = kblk * 544 + l31 * 16;
    int bb = kblk * 512 + l31 * 16;

#pragma unroll
    for (int i = 0; i < 7; ++i)
        gload16((const unsigned char*)wt + (tid + i * 256) * 16, Bs0 + (tid + i * 256) * 16);
    {
        const unsigned char* src = (const unsigned char*)xt +
            (size_t)(((n * TP + t) * DP + d) * HP + h0) * XT_ROW_B;
#pragma unroll
        for (int i = 0; i < 3; ++i)
            gload16(src + (tid + i * 256) * 16, As0 + (tid + i * 256) * 16);
    }
    asm volatile("s_waitcnt vmcnt(0)" ::: "memory");
    __syncthreads();

    f32x16 acc[2];
    acc[0] = {}; acc[1] = {};

#pragma unroll
    for (int p = 0; p < 9; ++p) {
        const int kt = p / 3, ph3 = p % 3;
        if (p < 8) {
            const int ktn = (p + 1) / 3, kdn = (p + 1) % 3;
            const unsigned char* src = (const unsigned char*)xt +
                (size_t)(((n * TP + t + ktn) * DP + d + kdn) * HP + h0) * XT_ROW_B;
            unsigned char* dst = ((p + 1) & 1) ? As1 : As0;
#pragma unroll
            for (int i = 0; i < 3; ++i)
                gload16(src + (tid + i * 256) * 16, dst + (tid + i * 256) * 16);
        }
        const bool bstage = (kt < 2) && (ph3 <= 1);
        if (bstage) {
            const int basel = ph3 * 896;
            const unsigned char* bsrc = (const unsigned char*)wt +
                (size_t)((kt + 1) * 27 * 64 + basel) * 16;
            unsigned char* bdst = (((kt + 1) & 1) ? Bs1 : Bs0) + basel * 16;
#pragma unroll
            for (int i = 0; i < 3; ++i)
                gload16(bsrc + (tid + i * 256) * 16, bdst + (tid + i * 256) * 16);
            if (tid < 128)
                gload16(bsrc + (tid + 768) * 16, bdst + (tid + 768) * 16);
        }

        const unsigned char* A = (p & 1) ? As1 : As0;
        const unsigned char* B = (kt & 1) ? Bs1 : Bs0;
        const int kd = ph3;

        bf16x8 bf[3][3];
#pragma unroll
        for (int kh = 0; kh < 3; ++kh)
#pragma unroll
            for (int kw = 0; kw < 3; ++kw)
                bf[kh][kw] = *(const bf16x8*)(B + ((kd * 9 + kh * 3 + kw) << 10) + bb);

#pragma unroll
        for (int rr = 0; rr < 4; ++rr) {
#pragma unroll
            for (int kw = 0; kw < 3; ++kw) {
                bf16x8 a = *(const bf16x8*)(A + (2 * wv + rr) * 1088 + ab + kw * 16);
#pragma unroll
                for (int kh = 0; kh < 3; ++kh) {
                    const int m = rr - kh;
                    if (m >= 0 && m < 2)
                        acc[m] = __builtin_amdgcn_mfma_f32_32x32x16_bf16(a, bf[kh][kw], acc[m], 0, 0, 0);
                }
            }
        }

        if (bstage)
            asm volatile("s_waitcnt vmcnt(4)" ::: "memory");
        else
            asm volatile("s_waitcnt vmcnt(0)" ::: "memory");
        __syncthreads();
    }

    float bsv = bias[l31];
#pragma unroll
    for (int m = 0; m < 2; ++m) {
        int oh = h0 + 2 * wv + m;
        float* obase = out + (((((size_t)n * OUT_C + l31) * TT + t) * DD + d) * HH + oh) * WW;
#pragma unroll
        for (int q = 0; q < 4; ++q) {
            f32x4 v = { acc[m][4 * q + 0] + bsv, acc[m][4 * q + 1] + bsv,
                        acc[m][4 * q + 2] + bsv, acc[m][4 * q + 3] + bsv };
            *(f32x4*)(obase + 8 * q + 4 * kblk) = v;
        }
    }
}

// ================= PROBE S: staging only (R10 staging, no compute), rep x6 ============
__global__ __launch_bounds__(256, 2) void probe_stage_kernel(const unsigned short* __restrict__ xt,
                                                             const unsigned short* __restrict__ wt,
                                                             float* __restrict__ scratch) {
    __shared__ __align__(16) unsigned char As0[A_SLAB_B];
    __shared__ __align__(16) unsigned char As1[A_SLAB_B];
    __shared__ __align__(16) unsigned char Bs0[B_CHUNK_B];
    __shared__ __align__(16) unsigned char Bs1[B_CHUNK_B];

    int bid = blockIdx.x;
    int lb  = (bid & 7) * 64 + (bid >> 3);
    int hb = lb & 3, d = (lb >> 2) & 7, t = (lb >> 5) & 7, n = lb >> 8;
    int h0 = hb * 8;
    int tid = threadIdx.x;

#pragma unroll 1
    for (int rep = 0; rep < 6; ++rep) {
#pragma unroll
        for (int i = 0; i < 7; ++i)
            gload16((const unsigned char*)wt + (tid + i * 256) * 16, Bs0 + (tid + i * 256) * 16);
        {
            const unsigned char* src = (const unsigned char*)xt +
                (size_t)(((n * TP + t) * DP + d) * HP + h0) * XT_ROW_B;
#pragma unroll
            for (int i = 0; i < 3; ++i)
                gload16(src + (tid + i * 256) * 16, As0 + (tid + i * 256) * 16);
        }
        asm volatile("s_waitcnt vmcnt(0)" ::: "memory");
        __syncthreads();

#pragma unroll
        for (int p = 0; p < 9; ++p) {
            const int kt = p / 3, ph3 = p % 3;
            if (p < 8) {
                const int ktn = (p + 1) / 3, kdn = (p + 1) % 3;
                const unsigned char* src = (const unsigned char*)xt +
                    (size_t)(((n * TP + t + ktn) * DP + d + kdn) * HP + h0) * XT_ROW_B;
                unsigned char* dst = ((p + 1) & 1) ? As1 : As0;
#pragma unroll
                for (int i = 0; i < 3; ++i)
                    gload16(src + (tid + i * 256) * 16, dst + (tid + i * 256) * 16);
            }
            const bool bstage = (kt < 2) && (ph3 <= 1);
            if (bstage) {
                const int basel = ph3 * 896;
                const unsigned char* bsrc = (const unsigned char*)wt +
                    (size_t)((kt + 1) * 27 * 64 + basel) * 16;
                unsigned char* bdst = (((kt + 1) & 1) ? Bs1 : Bs0) + basel * 16;
#pragma unroll
                for (int i = 0; i < 3; ++i)
                    gload16(bsrc + (tid + i * 256) * 16, bdst + (tid + i * 256) * 16);
                if (tid < 128)
                    gload16(bsrc + (tid + 768) * 16, bdst + (tid + 768) * 16);
            }
            if (bstage)
                asm volatile("s_waitcnt vmcnt(4)" ::: "memory");
            else
                asm volatile("s_waitcnt vmcnt(0)" ::: "memory");
            __syncthreads();
        }
        __syncthreads();
    }
    // consume LDS (deterministic; prevents any cleverness)
    scratch[(size_t)bid * 256 + tid] =
        ((const float*)As0)[tid] + ((const float*)As1)[tid] +
        ((const float*)Bs0)[tid] + ((const float*)Bs1)[tid];
}

// ================= PROBE C: compute only (stage once, no global in loop), rep x12 =====
__global__ __launch_bounds__(256, 2) void probe_comp_kernel(const unsigned short* __restrict__ xt,
                                                            const unsigned short* __restrict__ wt,
                                                            float* __restrict__ scratch) {
    __shared__ __align__(16) unsigned char As0[A_SLAB_B];
    __shared__ __align__(16) unsigned char Bs0[B_CHUNK_B];

    int bid = blockIdx.x;
    int lb  = (bid & 7) * 64 + (bid >> 3);
    int hb = lb & 3, d = (lb >> 2) & 7, t = (lb >> 5) & 7, n = lb >> 8;
    int h0 = hb * 8;
    int tid  = threadIdx.x;
    int wv   = tid >> 6;
    int lane = tid & 63;
    int l31  = lane & 31;
    int kblk = lane >> 5;

    int ab = kblk * 544 + l31 * 16;
    int bb = kblk * 512 + l31 * 16;

    // stage once
#pragma unroll
    for (int i = 0; i < 7; ++i)
        gload16((const unsigned char*)wt + (tid + i * 256) * 16, Bs0 + (tid + i * 256) * 16);
    {
        const unsigned char* src = (const unsigned char*)xt +
            (size_t)(((n * TP + t) * DP + d) * HP + h0) * XT_ROW_B;
#pragma unroll
        for (int i = 0; i < 3; ++i)
            gload16(src + (tid + i * 256) * 16, As0 + (tid + i * 256) * 16);
    }
    asm volatile("s_waitcnt vmcnt(0)" ::: "memory");
    __syncthreads();

    f32x16 acc[2];
    acc[0] = {}; acc[1] = {};

#pragma unroll 1
    for (int rep = 0; rep < 12; ++rep) {
        acc[0] = {}; acc[1] = {};
#pragma unroll
        for (int p = 0; p < 9; ++p) {
            const int kd = p % 3;
            bf16x8 bf[3][3];
#pragma unroll
            for (int kh = 0; kh < 3; ++kh)
#pragma unroll
                for (int kw = 0; kw < 3; ++kw)
                    bf[kh][kw] = *(const bf16x8*)(Bs0 + ((kd * 9 + kh * 3 + kw) << 10) + bb);
#pragma unroll
            for (int rr = 0; rr < 4; ++rr) {
#pragma unroll
                for (int kw = 0; kw < 3; ++kw) {
                    bf16x8 a = *(const bf16x8*)(As0 + (2 * wv + rr) * 1088 + ab + kw * 16);
#pragma unroll
                    for (int kh = 0; kh < 3; ++kh) {
                        const int m = rr - kh;
                        if (m >= 0 && m < 2)
                            acc[m] = __builtin_amdgcn_mfma_f32_32x32x16_bf16(a, bf[kh][kw], acc[m], 0, 0, 0);
                    }
                }
            }
            __syncthreads();
        }
    }

    float* sb = scratch + (size_t)bid * 2048 + tid * 8;
#pragma unroll
    for (int m = 0; m < 2; ++m) {
        f32x4 v = { acc[m][0], acc[m][4], acc[m][8], acc[m][12] };
        *(f32x4*)(sb + m * 4) = v;
    }
}

// ================= PROBE F: full R10 body, rep x3, output to scratch ==================
__global__ __launch_bounds__(256, 2) void probe_full_kernel(const unsigned short* __restrict__ xt,
                                                            const unsigned short* __restrict__ wt,
                                                            float* __restrict__ scratch) {
    __shared__ __align__(16) unsigned char As0[A_SLAB_B];
    __shared__ __align__(16) unsigned char As1[A_SLAB_B];
    __shared__ __align__(16) unsigned char Bs0[B_CHUNK_B];
    __shared__ __align__(16) unsigned char Bs1[B_CHUNK_B];

    int bid = blockIdx.x;
    int lb  = (bid & 7) * 64 + (bid >> 3);
    int hb = lb & 3, d = (lb >> 2) & 7, t = (lb >> 5) & 7, n = lb >> 8;
    int h0 = hb * 8;
    int tid  = threadIdx.x;
    int wv   = tid >> 6;
    int lane = tid & 63;
    int l31  = lane & 31;
    int kblk = lane >> 5;

    int ab = kblk * 544 + l31 * 16;
    int bb = kblk * 512 + l31 * 16;

    f32x16 acc[2];

#pragma unroll 1
    for (int rep = 0; rep < 3; ++rep) {
#pragma unroll
        for (int i = 0; i < 7; ++i)
            gload16((const unsigned char*)wt + (tid + i * 256) * 16, Bs0 + (tid + i * 256) * 16);
        {
            const unsigned char* src = (const unsigned char*)xt +
                (size_t)(((n * TP + t) * DP + d) * HP + h0) * XT_ROW_B;
#pragma unroll
            for (int i = 0; i < 3; ++i)
                gload16(src + (tid + i * 256) * 16, As0 + (tid + i * 256) * 16);
        }
        asm volatile("s_waitcnt vmcnt(0)" ::: "memory");
        __syncthreads();

        acc[0] = {}; acc[1] = {};
#pragma unroll
        for (int p = 0; p < 9; ++p) {
            const int kt = p / 3, ph3 = p % 3;
            if (p < 8) {
                const int ktn = (p + 1) / 3, kdn = (p + 1) % 3;
                const unsigned char* src = (const unsigned char*)xt +
                    (size_t)(((n * TP + t + ktn) * DP + d + kdn) * HP + h0) * XT_ROW_B;
                unsigned char* dst = ((p + 1) & 1) ? As1 : As0;
#pragma unroll
                for (int i = 0; i < 3; ++i)
                    gload16(src + (tid + i * 256) * 16, dst + (tid + i * 256) * 16);
            }
            const bool bstage = (kt < 2) && (ph3 <= 1);
            if (bstage) {
                const int basel = ph3 * 896;
                const unsigned char* bsrc = (const unsigned char*)wt +
                    (size_t)((kt + 1) * 27 * 64 + basel) * 16;
                unsigned char* bdst = (((kt + 1) & 1) ? Bs1 : Bs0) + basel * 16;
#pragma unroll
                for (int i = 0; i < 3; ++i)
                    gload16(bsrc + (tid + i * 256) * 16, bdst + (tid + i * 256) * 16);
                if (tid < 128)
                    gload16(bsrc + (tid + 768) * 16, bdst + (tid + 768) * 16);
            }

            const unsigned char* A = (p & 1) ? As1 : As0;
            const unsigned char* B = (kt & 1) ? Bs1 : Bs0;
            const int kd = ph3;

            bf16x8 bf[3][3];
#pragma unroll
            for (int kh = 0; kh < 3; ++kh)
#pragma unroll
                for (int kw = 0; kw < 3; ++kw)
                    bf[kh][kw] = *(const bf16x8*)(B + ((kd * 9 + kh * 3 + kw) << 10) + bb);

#pragma unroll
            for (int rr = 0; rr < 4; ++rr) {
#pragma unroll
                for (int kw = 0; kw < 3; ++kw) {
                    bf16x8 a = *(const bf16x8*)(A + (2 * wv + rr) * 1088 + ab + kw * 16);
#pragma unroll
                    for (int kh = 0; kh < 3; ++kh) {
                        const int m = rr - kh;
                        if (m >= 0 && m < 2)
                            acc[m] = __builtin_amdgcn_mfma_f32_32x32x16_bf16(a, bf[kh][kw], acc[m], 0, 0, 0);
                    }
                }
            }

            if (bstage)
                asm volatile("s_waitcnt vmcnt(4)" ::: "memory");
            else
                asm volatile("s_waitcnt vmcnt(0)" ::: "memory");
            __syncthreads();
        }
        __syncthreads();
    }

    float* sb = scratch + (size_t)bid * 2048 + tid * 8;
#pragma unroll
    for (int m = 0; m < 2; ++m) {
        f32x4 v = { acc[m][0], acc[m][4], acc[m][8], acc[m][12] };
        *(f32x4*)(sb + m * 4) = v;
    }
}

extern "C" void kernel_launch(void* const* d_in, const int* in_sizes, int n_in,
                              void* d_out, int out_size, void* d_ws, size_t ws_size,
                              hipStream_t stream) {
    const float* x    = (const float*)d_in[0];
    const float* wsrc = (const float*)d_in[1];
    const float* bias = (const float*)d_in[2];
    float* out        = (float*)d_out;

    unsigned short* xt = (unsigned short*)d_ws;
    unsigned short* wt = xt + XT_ELEMS;

    prep_kernel<<<4096 + 2704 + 164, 256, 0, stream>>>(x, wsrc, xt, wt);
    conv_main_kernel<<<NB * TT * DD * 4, 256, 0, stream>>>(xt, wt, bias, out);

    // ---- measurement probes (write to scratch, far past xt+wt) ----
    float* sS = (float*)((char*)d_ws + (64u << 20));
    float* sC = (float*)((char*)d_ws + (80u << 20));
    float* sF = (float*)((char*)d_ws + (96u << 20));
    probe_stage_kernel<<<NB * TT * DD * 4, 256, 0, stream>>>(xt, wt, sS);
    probe_comp_kernel<<<NB * TT * DD * 4, 256, 0, stream>>>(xt, wt, sC);
    probe_full_kernel<<<NB * TT * DD * 4, 256, 0, stream>>>(xt, wt, sF);
}

// Round 17
// 28.662 us; speedup vs baseline: 5.8688x; 5.8688x over previous
//
#include <hip/hip_runtime.h>

// ---- problem constants ----
#define IN_C  16
#define OUT_C 32
#define NB 2
#define TT 8
#define DD 8
#define HH 32
#define WW 32
#define TP 10
#define DP 10
#define HP 34
#define WPAD 34

// xt layout: [n][tp][dp][hp][icblk(2)][w(34)][ic8] bf16 ; row = 1088 B
#define XT_ROW_B  1088
#define XT_ELEMS  (NB*TP*DP*HP*2*WPAD*8)     // 3,699,200 bf16 = 7,398,400 B
// wt layout: [tap(84 padded)][icblk(2)][oc(32)][ic8] bf16 ; taps 81..83 zeroed
#define WT_TAPS_P 84
#define WT_ELEMS  (WT_TAPS_P*2*OUT_C*8)      // 43,008 bf16 = 86,016 B

// Per-plane LDS slabs, TRIPLE buffered (staged 2 planes ahead):
// A = 10 rows x 1088 B = 680 lines, padded to 768 (6 x 128-thr rounds)
// B = 9 taps x 1024 B = 576 lines, padded to 640 (5 x 128-thr rounds)
#define A_SLAB_B 12288
#define B_SLAB_B 10240

typedef __bf16 bf16x8 __attribute__((ext_vector_type(8)));
typedef float  f32x4  __attribute__((ext_vector_type(4)));
typedef float  f32x16 __attribute__((ext_vector_type(16)));

__device__ __forceinline__ unsigned short f2bf(float f) {
    unsigned int u = __builtin_bit_cast(unsigned int, f);
    u += 0x7fffu + ((u >> 16) & 1u);       // RNE
    return (unsigned short)(u >> 16);
}

__device__ __forceinline__ void gload16(const void* g, void* l) {
    __builtin_amdgcn_global_load_lds(
        (const __attribute__((address_space(1))) unsigned int*)g,
        (__attribute__((address_space(3))) unsigned int*)l, 16, 0, 0);
}

// ---------------- fused prep: xpose rows + halo zeroing + weight xform ----------------
__global__ __launch_bounds__(256) void prep_kernel(const float* __restrict__ x,
                                                   const float* __restrict__ wsrc,
                                                   unsigned short* __restrict__ xt,
                                                   unsigned short* __restrict__ wt) {
    int b = blockIdx.x;
    int tid = threadIdx.x;
    if (b < 4096) {
        __shared__ unsigned short ls[WW * IN_C];   // [w][c], 1 KiB
        int h = b & 31, d = (b >> 5) & 7, t = (b >> 8) & 7, n = b >> 11;
        int c = tid >> 5, w = tid & 31;
        float v0 = x[((((size_t)(n * IN_C + c)     * TT + t) * DD + d) * HH + h) * WW + w];
        float v1 = x[((((size_t)(n * IN_C + c + 8) * TT + t) * DD + d) * HH + h) * WW + w];
        ls[w * 16 + c]     = f2bf(v0);
        ls[w * 16 + c + 8] = f2bf(v1);
        __syncthreads();
        if (tid < 68) {                 // line = blk*34 + wl
            int blk = tid / 34, wl = tid % 34;
            unsigned char* row = (unsigned char*)xt +
                (size_t)(((n * TP + t + 1) * DP + d + 1) * HP + h + 1) * XT_ROW_B;
            f32x4 val = {0.f, 0.f, 0.f, 0.f};
            if (wl != 0 && wl != 33)
                val = *(const f32x4*)((const unsigned char*)ls + (wl - 1) * 32 + blk * 16);
            *(f32x4*)(row + tid * 16) = val;
        }
    } else if (b < 6800) {
        int j = b - 4096;               // 2704 halo rows
        int n, tp, dp, hp;
        if (j < 1360)      { n = j / 680;  int r = j % 680;  tp = (r / 340) * 9; int r2 = r % 340; dp = r2 / 34;       hp = r2 % 34; }
        else if (j < 2448) { int j2 = j - 1360; n = j2 / 544; int r = j2 % 544; tp = 1 + r / 68;  int r3 = r % 68;  dp = (r3 / 34) * 9; hp = r3 % 34; }
        else               { int j3 = j - 2448; n = j3 / 128; int r = j3 % 128; tp = 1 + r / 16;  int r4 = r % 16;  dp = 1 + r4 / 2;   hp = (r4 & 1) * 33; }
        if (tid < 68) {
            unsigned char* row = (unsigned char*)xt +
                (size_t)(((n * TP + tp) * DP + dp) * HP + hp) * XT_ROW_B;
            f32x4 z = {0.f, 0.f, 0.f, 0.f};
            *(f32x4*)(row + tid * 16) = z;
        }
    } else {
        int idx = (b - 6800) * 256 + tid;   // 0..43007
        int tap = idx >> 9;
        int r = idx & 511;
        int icblk = r >> 8, oc = (r >> 3) & 31, i8 = r & 7;
        int ic = icblk * 8 + i8;
        float v = (tap < 81) ? wsrc[(oc * IN_C + ic) * 81 + tap] : 0.0f;
        wt[idx] = f2bf(v);
    }
}

// ---------------- main: M_rep=4, triple-buffer 2-ahead, counted vmcnt(11) ----------
// block = 2 waves (128 thr); wave wm owns output rows h0+4wm..+3 (M_rep=4).
// Per phase per wave: 9 B + 18 A ds_read_b128 feed 36 MFMAs (0.75 reads/MFMA).
// Per-plane A (768 lines) + B (640 lines) slabs, triple-buffered, staged TWO
// planes ahead; end-of-phase s_waitcnt vmcnt(11) drains only plane p+1 -- the
// newest plane's 11 loads (and their LDS-DMA writes) get 2 full phases to land.
// Grid 512 -> 2 blocks/CU (LDS 67,584 B/block).
__global__ __launch_bounds__(128, 1) void conv_main_kernel(const unsigned short* __restrict__ xt,
                                                           const unsigned short* __restrict__ wt,
                                                           const float* __restrict__ bias,
                                                           float* __restrict__ out) {
    __shared__ __align__(16) unsigned char As[3][A_SLAB_B];   // 36,864 B
    __shared__ __align__(16) unsigned char Bs[3][B_SLAB_B];   // 30,720 B

    int bid = blockIdx.x;
    int lb  = (bid & 7) * 64 + (bid >> 3);   // XCD swizzle, bijective (512 % 8 == 0)
    int hb = lb & 3, d = (lb >> 2) & 7, t = (lb >> 5) & 7, n = lb >> 8;
    int h0 = hb * 8;
    int tid  = threadIdx.x;
    int wm   = tid >> 6;               // 0..1, owns output rows h0+4wm..+3
    int lane = tid & 63;
    int l31  = lane & 31;
    int kblk = lane >> 5;

    int ab = kblk * 544 + l31 * 16;    // A-frag lane offset within a row
    int bb = kblk * 512 + l31 * 16;    // B-frag lane offset within a tap

    // stage plane p: A -> As[p%3] (6 rounds), B(9 taps) -> Bs[p%3] (5 rounds)
    auto issueP = [&](int p) {
        const unsigned char* srcA = (const unsigned char*)xt +
            (size_t)(((n * TP + t + p / 3) * DP + d + p % 3) * HP + h0) * XT_ROW_B;
        unsigned char* dstA = As[p % 3];
#pragma unroll
        for (int i = 0; i < 6; ++i)
            gload16(srcA + (tid + i * 128) * 16, dstA + (tid + i * 128) * 16);
        const unsigned char* srcB = (const unsigned char*)wt + (size_t)p * 9 * 1024;
        unsigned char* dstB = Bs[p % 3];
#pragma unroll
        for (int i = 0; i < 5; ++i)
            gload16(srcB + (tid + i * 128) * 16, dstB + (tid + i * 128) * 16);
    };

    // ---- prologue: planes 0 and 1 in flight; wait for plane 0 only ----
    issueP(0);
    issueP(1);
    asm volatile("s_waitcnt vmcnt(11)" ::: "memory");
    __syncthreads();

    f32x16 acc[4];
#pragma unroll
    for (int m = 0; m < 4; ++m) acc[m] = {};

#pragma unroll
    for (int p = 0; p < 9; ++p) {
        // ---- 1. stage plane p+2 (buffer (p+2)%3: last read at p-1, barrier-safe) ----
        if (p + 2 <= 8) issueP(p + 2);

        // ---- 2. compute plane p from As[p%3], Bs[p%3] ----
        const unsigned char* Ab = As[p % 3];
        const unsigned char* Bb = Bs[p % 3];
        bf16x8 bf[9];
#pragma unroll
        for (int j = 0; j < 9; ++j)
            bf[j] = *(const bf16x8*)(Bb + j * 1024 + bb);
#pragma unroll
        for (int kw = 0; kw < 3; ++kw) {
#pragma unroll
            for (int r = 0; r < 6; ++r) {
                bf16x8 a = *(const bf16x8*)(Ab + (4 * wm + r) * 1088 + ab + kw * 16);
#pragma unroll
                for (int kh = 0; kh < 3; ++kh) {
                    const int m = r - kh;
                    if (m >= 0 && m < 4)
                        acc[m] = __builtin_amdgcn_mfma_f32_32x32x16_bf16(a, bf[kh * 3 + kw], acc[m], 0, 0, 0);
                }
            }
        }

        // ---- 3. counted wait: drain plane p+1 (for next phase); plane p+2 flies ----
        if (p + 2 <= 8)
            asm volatile("s_waitcnt vmcnt(11)" ::: "memory");
        else
            asm volatile("s_waitcnt vmcnt(0)" ::: "memory");
        __syncthreads();
    }

    // ---- epilogue: col(oc)=l31, row(w)=(reg&3)+8*(reg>>2)+4*kblk ----
    float bsv = bias[l31];
#pragma unroll
    for (int m = 0; m < 4; ++m) {
        int oh = h0 + 4 * wm + m;
        float* obase = out + (((((size_t)n * OUT_C + l31) * TT + t) * DD + d) * HH + oh) * WW;
#pragma unroll
        for (int q = 0; q < 4; ++q) {
            f32x4 v = { acc[m][4 * q + 0] + bsv, acc[m][4 * q + 1] + bsv,
                        acc[m][4 * q + 2] + bsv, acc[m][4 * q + 3] + bsv };
            *(f32x4*)(obase + 8 * q + 4 * kblk) = v;
        }
    }
}

extern "C" void kernel_launch(void* const* d_in, const int* in_sizes, int n_in,
                              void* d_out, int out_size, void* d_ws, size_t ws_size,
                              hipStream_t stream) {
    const float* x    = (const float*)d_in[0];
    const float* wsrc = (const float*)d_in[1];
    const float* bias = (const float*)d_in[2];
    float* out        = (float*)d_out;

    unsigned short* xt = (unsigned short*)d_ws;
    unsigned short* wt = xt + XT_ELEMS;

    prep_kernel<<<4096 + 2704 + 164, 256, 0, stream>>>(x, wsrc, xt, wt);
    conv_main_kernel<<<NB * TT * DD * 4, 128, 0, stream>>>(xt, wt, bias, out);
}

// Round 18
// 28.428 us; speedup vs baseline: 5.9172x; 1.0082x over previous
//
#include <hip/hip_runtime.h>

// ---- problem constants ----
#define IN_C  16
#define OUT_C 32
#define NB 2
#define TT 8
#define DD 8
#define HH 32
#define WW 32
#define TP 10
#define DP 10
#define HP 34
#define WPAD 34

// xt layout: [n][tp][dp][hp][icblk(2)][w(34)][ic8] bf16 ; row = 1088 B
#define XT_ROW_B  1088
#define XT_ELEMS  (NB*TP*DP*HP*2*WPAD*8)     // 3,699,200 bf16 = 7,398,400 B
// wt layout: [tap(84 padded)][icblk(2)][oc(32)][ic8] bf16 ; taps 81..83 zeroed
#define WT_TAPS_P 84
#define WT_ELEMS  (WT_TAPS_P*2*OUT_C*8)      // 43,008 bf16 = 86,016 B

// Per-plane slabs, TRIPLE buffered, staged 2 planes ahead.
// A slab: 10 rows x 1088 B = 680 lines, padded to 768 (3 x 256-thr rounds).
// B slab: 9 taps x 1024 B = 576 lines, padded to 768 (3 rounds; junk lines
// read past plane p but stay inside wt: p*9216 + 12288 <= 86016 for p <= 8).
#define SLAB_B 12288

typedef __bf16 bf16x8 __attribute__((ext_vector_type(8)));
typedef float  f32x4  __attribute__((ext_vector_type(4)));
typedef float  f32x16 __attribute__((ext_vector_type(16)));

__device__ __forceinline__ unsigned short f2bf(float f) {
    unsigned int u = __builtin_bit_cast(unsigned int, f);
    u += 0x7fffu + ((u >> 16) & 1u);       // RNE
    return (unsigned short)(u >> 16);
}

__device__ __forceinline__ void gload16(const void* g, void* l) {
    __builtin_amdgcn_global_load_lds(
        (const __attribute__((address_space(1))) unsigned int*)g,
        (__attribute__((address_space(3))) unsigned int*)l, 16, 0, 0);
}

// ---------------- fused prep: xpose rows + halo zeroing + weight xform ----------------
__global__ __launch_bounds__(256) void prep_kernel(const float* __restrict__ x,
                                                   const float* __restrict__ wsrc,
                                                   unsigned short* __restrict__ xt,
                                                   unsigned short* __restrict__ wt) {
    int b = blockIdx.x;
    int tid = threadIdx.x;
    if (b < 4096) {
        __shared__ unsigned short ls[WW * IN_C];   // [w][c], 1 KiB
        int h = b & 31, d = (b >> 5) & 7, t = (b >> 8) & 7, n = b >> 11;
        int c = tid >> 5, w = tid & 31;
        float v0 = x[((((size_t)(n * IN_C + c)     * TT + t) * DD + d) * HH + h) * WW + w];
        float v1 = x[((((size_t)(n * IN_C + c + 8) * TT + t) * DD + d) * HH + h) * WW + w];
        ls[w * 16 + c]     = f2bf(v0);
        ls[w * 16 + c + 8] = f2bf(v1);
        __syncthreads();
        if (tid < 68) {                 // line = blk*34 + wl
            int blk = tid / 34, wl = tid % 34;
            unsigned char* row = (unsigned char*)xt +
                (size_t)(((n * TP + t + 1) * DP + d + 1) * HP + h + 1) * XT_ROW_B;
            f32x4 val = {0.f, 0.f, 0.f, 0.f};
            if (wl != 0 && wl != 33)
                val = *(const f32x4*)((const unsigned char*)ls + (wl - 1) * 32 + blk * 16);
            *(f32x4*)(row + tid * 16) = val;
        }
    } else if (b < 6800) {
        int j = b - 4096;               // 2704 halo rows
        int n, tp, dp, hp;
        if (j < 1360)      { n = j / 680;  int r = j % 680;  tp = (r / 340) * 9; int r2 = r % 340; dp = r2 / 34;       hp = r2 % 34; }
        else if (j < 2448) { int j2 = j - 1360; n = j2 / 544; int r = j2 % 544; tp = 1 + r / 68;  int r3 = r % 68;  dp = (r3 / 34) * 9; hp = r3 % 34; }
        else               { int j3 = j - 2448; n = j3 / 128; int r = j3 % 128; tp = 1 + r / 16;  int r4 = r % 16;  dp = 1 + r4 / 2;   hp = (r4 & 1) * 33; }
        if (tid < 68) {
            unsigned char* row = (unsigned char*)xt +
                (size_t)(((n * TP + tp) * DP + dp) * HP + hp) * XT_ROW_B;
            f32x4 z = {0.f, 0.f, 0.f, 0.f};
            *(f32x4*)(row + tid * 16) = z;
        }
    } else {
        int idx = (b - 6800) * 256 + tid;   // 0..43007
        int tap = idx >> 9;
        int r = idx & 511;
        int icblk = r >> 8, oc = (r >> 3) & 31, i8 = r & 7;
        int ic = icblk * 8 + i8;
        float v = (tap < 81) ? wsrc[(oc * IN_C + ic) * 81 + tap] : 0.0f;
        wt[idx] = f2bf(v);
    }
}

// ---------------- main: M_rep=2 / 8 waves/CU (R10 compute) + 2-ahead triple-buffer ---
// block = 4 waves (256 thr); wave owns output rows h0+2wv, +1. Per phase per wave:
// 9 B + 12 A ds_read_b128 -> 18 MFMA (the measured-optimal 1.17 reads/MFMA at
// 8 waves/CU). Staging: per-plane A+B slabs, triple-buffered, issued TWO planes
// ahead (6 gloads/thread/phase, uniform); end-of-phase s_waitcnt vmcnt(6) drains
// plane p+1 (issued 2 phases ago) while plane p+2 stays in flight. setprio(1)
// around the compute cluster (T5: pays in phase-split counted-vmcnt schedules).
__global__ __launch_bounds__(256, 2) void conv_main_kernel(const unsigned short* __restrict__ xt,
                                                           const unsigned short* __restrict__ wt,
                                                           const float* __restrict__ bias,
                                                           float* __restrict__ out) {
    __shared__ __align__(16) unsigned char As[3][SLAB_B];   // 36,864 B
    __shared__ __align__(16) unsigned char Bs[3][SLAB_B];   // 36,864 B

    int bid = blockIdx.x;
    int lb  = (bid & 7) * 64 + (bid >> 3);   // XCD swizzle, bijective (512 % 8 == 0)
    int hb = lb & 3, d = (lb >> 2) & 7, t = (lb >> 5) & 7, n = lb >> 8;
    int h0 = hb * 8;
    int tid  = threadIdx.x;
    int wv   = tid >> 6;               // 0..3, owns output rows h0+2wv, +1
    int lane = tid & 63;
    int l31  = lane & 31;
    int kblk = lane >> 5;

    int ab = kblk * 544 + l31 * 16;    // A-frag lane offset within a row
    int bb = kblk * 512 + l31 * 16;    // B-frag lane offset within a tap

    // stage plane p: A -> As[p%3], B(9 taps) -> Bs[p%3]; 3+3 uniform rounds
    auto issueP = [&](int p) {
        const unsigned char* srcA = (const unsigned char*)xt +
            (size_t)(((n * TP + t + p / 3) * DP + d + p % 3) * HP + h0) * XT_ROW_B;
        unsigned char* dstA = As[p % 3];
#pragma unroll
        for (int i = 0; i < 3; ++i)
            gload16(srcA + (tid + i * 256) * 16, dstA + (tid + i * 256) * 16);
        const unsigned char* srcB = (const unsigned char*)wt + (size_t)p * 9216;
        unsigned char* dstB = Bs[p % 3];
#pragma unroll
        for (int i = 0; i < 3; ++i)
            gload16(srcB + (tid + i * 256) * 16, dstB + (tid + i * 256) * 16);
    };

    // ---- prologue: planes 0,1 in flight; drain plane 0 only ----
    issueP(0);
    issueP(1);
    asm volatile("s_waitcnt vmcnt(6)" ::: "memory");
    __syncthreads();

    f32x16 acc[2];
    acc[0] = {}; acc[1] = {};

#pragma unroll
    for (int p = 0; p < 9; ++p) {
        // ---- 1. issue plane p+2 (slab (p+2)%3 last read in phase p-1: safe) ----
        if (p < 7) issueP(p + 2);

        // ---- 2. compute plane p from As[p%3], Bs[p%3] ----
        const unsigned char* A = As[p % 3];
        const unsigned char* B = Bs[p % 3];

        __builtin_amdgcn_s_setprio(1);
        bf16x8 bf[3][3];
#pragma unroll
        for (int kh = 0; kh < 3; ++kh)
#pragma unroll
            for (int kw = 0; kw < 3; ++kw)
                bf[kh][kw] = *(const bf16x8*)(B + ((kh * 3 + kw) << 10) + bb);

#pragma unroll
        for (int rr = 0; rr < 4; ++rr) {       // input rows 2wv+rr
#pragma unroll
            for (int kw = 0; kw < 3; ++kw) {
                bf16x8 a = *(const bf16x8*)(A + (2 * wv + rr) * 1088 + ab + kw * 16);
#pragma unroll
                for (int kh = 0; kh < 3; ++kh) {
                    const int m = rr - kh;
                    if (m >= 0 && m < 2)
                        acc[m] = __builtin_amdgcn_mfma_f32_32x32x16_bf16(a, bf[kh][kw], acc[m], 0, 0, 0);
                }
            }
        }
        __builtin_amdgcn_s_setprio(0);

        // ---- 3. counted wait: drain plane p+1; plane p+2 keeps flying ----
        if (p < 7)
            asm volatile("s_waitcnt vmcnt(6)" ::: "memory");
        else
            asm volatile("s_waitcnt vmcnt(0)" ::: "memory");
        __syncthreads();
    }

    // ---- epilogue: col(oc)=l31, row(w)=(reg&3)+8*(reg>>2)+4*kblk ----
    float bsv = bias[l31];
#pragma unroll
    for (int m = 0; m < 2; ++m) {
        int oh = h0 + 2 * wv + m;
        float* obase = out + (((((size_t)n * OUT_C + l31) * TT + t) * DD + d) * HH + oh) * WW;
#pragma unroll
        for (int q = 0; q < 4; ++q) {
            f32x4 v = { acc[m][4 * q + 0] + bsv, acc[m][4 * q + 1] + bsv,
                        acc[m][4 * q + 2] + bsv, acc[m][4 * q + 3] + bsv };
            *(f32x4*)(obase + 8 * q + 4 * kblk) = v;
        }
    }
}

extern "C" void kernel_launch(void* const* d_in, const int* in_sizes, int n_in,
                              void* d_out, int out_size, void* d_ws, size_t ws_size,
                              hipStream_t stream) {
    const float* x    = (const float*)d_in[0];
    const float* wsrc = (const float*)d_in[1];
    const float* bias = (const float*)d_in[2];
    float* out        = (float*)d_out;

    unsigned short* xt = (unsigned short*)d_ws;
    unsigned short* wt = xt + XT_ELEMS;

    prep_kernel<<<4096 + 2704 + 164, 256, 0, stream>>>(x, wsrc, xt, wt);
    conv_main_kernel<<<NB * TT * DD * 4, 256, 0, stream>>>(xt, wt, bias, out);
}